// Round 7
// baseline (93.371 us; speedup 1.0000x reference)
//
#include <hip/hip_runtime.h>
#include <stdint.h>

namespace {

constexpr int kB = 16;
constexpr int kN = 1024;
constexpr int kF = 128;
constexpr int kHalf = kB * kN * kN;  // 16,777,216 == B*N*N; noise array is [2, B, N, N]

__device__ __forceinline__ uint32_t rotl32(uint32_t x, int r) {
  return (x << r) | (x >> (32 - r));
}

// JAX threefry2x32 with key = (0, 42)  [jax.random.key(42)]
__device__ __forceinline__ void tf2x32(uint32_t x0, uint32_t x1,
                                       uint32_t& o0, uint32_t& o1) {
  constexpr uint32_t ks0 = 0u;
  constexpr uint32_t ks1 = 42u;
  constexpr uint32_t ks2 = 0u ^ 42u ^ 0x1BD11BDAu;
  x0 += ks0; x1 += ks1;
#define TFR(r) { x0 += x1; x1 = rotl32(x1, (r)); x1 ^= x0; }
  TFR(13) TFR(15) TFR(26) TFR(6)
  x0 += ks1; x1 += ks2 + 1u;
  TFR(17) TFR(29) TFR(16) TFR(24)
  x0 += ks2; x1 += ks0 + 2u;
  TFR(13) TFR(15) TFR(26) TFR(6)
  x0 += ks0; x1 += ks1 + 3u;
  TFR(17) TFR(29) TFR(16) TFR(24)
  x0 += ks1; x1 += ks2 + 4u;
  TFR(13) TFR(15) TFR(26) TFR(6)
  x0 += ks2; x1 += ks0 + 5u;
#undef TFR
  o0 = x0; o1 = x1;
}

// partitionable mode: bits[idx] = o0 ^ o1 of threefry(key, (idx>>32, idx&0xffffffff))
__device__ __forceinline__ uint32_t random_bits_part(uint32_t idx) {
  uint32_t o0, o1;
  tf2x32(0u, idx, o0, o1);
  return o0 ^ o1;
}

// jax.random.uniform conversion: f in [0,1) from top-23 mantissa bits;
// u = max(1e-10f, f + 1e-10f)   ((maxval-minval) rounds to exactly 1.0f)
__device__ __forceinline__ float bits_to_uniform(uint32_t bits) {
  float f = __uint_as_float((bits >> 9) | 0x3F800000u) - 1.0f;
  return fmaxf(1e-10f, f + 1e-10f);
}

// ---------------------------------------------------------------------------
// Kernel 1: probs[b,i] = clip(sigmoid(leaky_relu([left_b, nodes_bi] @ W1 + b1) @ W2 + b2))
// Tiled f32 GEMM: 512 blocks x 256 threads, each block does 32 rows (one b).
// Result scattered into out_w[(b*N + i)*N + nn_b] (read-before-write staging).
// ---------------------------------------------------------------------------
__global__ __launch_bounds__(256) void mlp_probs_kernel(
    const float* __restrict__ nodes, const int* __restrict__ num_nodes,
    const float* __restrict__ W1, const float* __restrict__ b1,
    const float* __restrict__ W2, const float* __restrict__ b2,
    float* __restrict__ out_w) {
  __shared__ float xs[32][256];   // 32 KiB: per-row input [left(128) | nodes_row(128)]
  __shared__ float bt[16][128];   // 8 KiB: W1 K-tile
  __shared__ float hs[32][128];   // 16 KiB: hidden activations
  __shared__ float h2[32][8];     // 1 KiB: second-layer partials

  const int blk = blockIdx.x;      // 512 blocks = 16 b * 32 row-chunks
  const int b = blk >> 5;
  const int i0 = (blk & 31) * 32;
  const int t = threadIdx.x;
  const int nn = num_nodes[b];
  const float* nb = nodes + (size_t)b * kN * kF;
  const float* leftp = nb + (size_t)nn * kF;

  // stage X tile [32 rows][256]
  for (int chunk = 0; chunk < 16; ++chunk) {
    int idx = chunk * 256 + t;   // 0..4095
    int r = idx >> 7;            // 0..31
    int c = idx & 127;
    xs[r][c] = leftp[c];
    xs[r][128 + c] = nb[(size_t)(i0 + r) * kF + c];
  }

  const int tx = t & 31;   // 4 cols each -> 128 cols
  const int ty = t >> 5;   // 4 rows each -> 32 rows
  float acc[4][4];
#pragma unroll
  for (int rr = 0; rr < 4; ++rr)
#pragma unroll
    for (int cc = 0; cc < 4; ++cc) acc[rr][cc] = 0.0f;

  for (int k0 = 0; k0 < 256; k0 += 16) {
    __syncthreads();  // xs ready (first iter) / bt consumers done (later iters)
#pragma unroll
    for (int qq = 0; qq < 8; ++qq) {
      int idx = qq * 256 + t;    // 0..2047
      int kk = idx >> 7;         // 0..15
      int c = idx & 127;
      bt[kk][c] = W1[(size_t)(k0 + kk) * kF + c];
    }
    __syncthreads();
#pragma unroll
    for (int kk = 0; kk < 16; ++kk) {
      float bv0 = bt[kk][4 * tx + 0];
      float bv1 = bt[kk][4 * tx + 1];
      float bv2 = bt[kk][4 * tx + 2];
      float bv3 = bt[kk][4 * tx + 3];
#pragma unroll
      for (int rr = 0; rr < 4; ++rr) {
        float xv = xs[4 * ty + rr][k0 + kk];
        acc[rr][0] = fmaf(xv, bv0, acc[rr][0]);
        acc[rr][1] = fmaf(xv, bv1, acc[rr][1]);
        acc[rr][2] = fmaf(xv, bv2, acc[rr][2]);
        acc[rr][3] = fmaf(xv, bv3, acc[rr][3]);
      }
    }
  }

  // bias + leaky_relu(0.01) -> hs
#pragma unroll
  for (int rr = 0; rr < 4; ++rr)
#pragma unroll
    for (int cc = 0; cc < 4; ++cc) {
      float v = acc[rr][cc] + b1[4 * tx + cc];
      hs[4 * ty + rr][4 * tx + cc] = (v >= 0.0f) ? v : 0.01f * v;
    }
  __syncthreads();

  // second layer: z = hs @ W2 + b2 ; 8 partial sums of 16 per row
  {
    const int r = t >> 3;  // 0..31
    const int q = t & 7;   // 0..7
    float s = 0.0f;
#pragma unroll
    for (int j = 0; j < 16; ++j) {
      int k = q * 16 + j;
      s = fmaf(hs[r][k], W2[k], s);
    }
    h2[r][q] = s;
  }
  __syncthreads();

  if (t < 32) {
    float z = 0.0f;
#pragma unroll
    for (int q = 0; q < 8; ++q) z += h2[t][q];
    z += b2[0];
    double p = 1.0 / (1.0 + exp(-(double)z));  // high-accuracy sigmoid
    float pc = fminf(fmaxf((float)p, 0.001f), 0.999f);
    // stage into out_w at [b][i][nn]; kernel 2's owning thread reads it back
    out_w[(size_t)((b << 10) + i0 + t) * kN + nn] = pc;
  }
}

// ---------------------------------------------------------------------------
// Kernel 2: per (b,i,j): w, gumbel-softmax hard sample. 4 elements per thread.
//
// Decision (proved exact-math-equivalent in R2/R6, empirically 0 flips):
//   class1 <=> c1*L0 > c0*L1,  L_k = -logf(u_k)
// Hot path here uses raw v_log_f32 (__log2f; positive ln2 scale folded out):
//   D = c0*log2(u1) - c1*log2(u0);  class1 <=> D > 0
// Screen: |D| <= 0.01 (log2 units) -> recompute with the EXACT R6 OCML chain.
// Worst-case |D_fast - D_exact| <= 2 * 200ulp * ulp(33) ~= 1.5e-3 << 0.01,
// so screened decisions are bit-identical to the R6-passing kernel; ambiguous
// elements (~1.4e-2 probability) take the exact fallback (wave-masked, ~0 cost).
// ---------------------------------------------------------------------------
__global__ __launch_bounds__(256) void edge_sample_kernel(
    const float* __restrict__ weights, const int* __restrict__ num_nodes,
    float* __restrict__ out_adj, float* __restrict__ out_w) {
  const int tid = blockIdx.x * 256 + threadIdx.x;
  const int q0 = tid * 4;                 // grid sized exactly: q0 < kHalf
  const int b = q0 >> 20;                 // N*N = 2^20
  const int i = (q0 >> 10) & 1023;
  const int j0 = q0 & 1023;
  const int nn = num_nodes[b];
  const bool rowsel = (i < nn);
  const int rowbase = q0 - j0;            // (b*N + i)*N

  // p staged by kernel 1 at out_w[rowbase + nn]; only the thread whose quad
  // contains column nn needs it (it reads before it overwrites - same thread).
  float pv = 0.0f;
  if (rowsel && nn >= j0 && nn < j0 + 4) pv = out_w[rowbase + nn];

  const float4 wq = *reinterpret_cast<const float4*>(weights + q0);
  float wvals[4] = {wq.x, wq.y, wq.z, wq.w};
  float oa[4], ow[4];
  float u0s[4], u1s[4], c0s[4], c1s[4], Ds[4];
  bool need = false;

#pragma unroll
  for (int ee = 0; ee < 4; ++ee) {
    const int j = j0 + ee;
    const float w = (rowsel && (j == nn)) ? pv : wvals[ee];
    // clip([1-w, w], 0.001, 0.999)
    const float c1 = fminf(fmaxf(w, 0.001f), 0.999f);
    const float c0 = fminf(fmaxf(1.0f - w, 0.001f), 0.999f);

    const uint32_t idx0 = (uint32_t)(q0 + ee);          // noise[0,b,i,j]
    const float u0 = bits_to_uniform(random_bits_part(idx0));
    const float u1 = bits_to_uniform(random_bits_part(idx0 + (uint32_t)kHalf));

    // fast decision via hardware log2 (1 instr each)
    const float lf0 = __log2f(u0);
    const float lf1 = __log2f(u1);
    const float D = c0 * lf1 - c1 * lf0;  // > 0 -> class 1

    oa[ee] = (D > 0.0f) ? 1.0f : 0.0f;
    ow[ee] = w;
    u0s[ee] = u0; u1s[ee] = u1; c0s[ee] = c0; c1s[ee] = c1; Ds[ee] = D;
    need |= (fabsf(D) <= 0.01f);
  }

  if (need) {
    // exact path: identical arithmetic to the R6-passing kernel
#pragma unroll
    for (int ee = 0; ee < 4; ++ee) {
      if (fabsf(Ds[ee]) <= 0.01f) {
        const float L0 = -logf(u0s[ee]);   // OCML, faithful
        const float L1 = -logf(u1s[ee]);
        oa[ee] = (c1s[ee] * L0 > c0s[ee] * L1) ? 1.0f : 0.0f;
      }
    }
  }

  *reinterpret_cast<float4*>(out_adj + q0) = make_float4(oa[0], oa[1], oa[2], oa[3]);
  *reinterpret_cast<float4*>(out_w + q0) = make_float4(ow[0], ow[1], ow[2], ow[3]);
}

}  // namespace

extern "C" void kernel_launch(void* const* d_in, const int* in_sizes, int n_in,
                              void* d_out, int out_size, void* d_ws, size_t ws_size,
                              hipStream_t stream) {
  (void)in_sizes; (void)n_in; (void)d_ws; (void)ws_size; (void)out_size;
  const float* nodes = (const float*)d_in[0];
  // d_in[1] = adj (unused by reference)
  const float* weights = (const float*)d_in[2];
  const int* num_nodes = (const int*)d_in[3];
  // d_in[4] = B scalar (compile-time constant here)
  const float* W1 = (const float*)d_in[5];
  const float* b1 = (const float*)d_in[6];
  const float* W2 = (const float*)d_in[7];
  const float* b2 = (const float*)d_in[8];

  float* out_adj = (float*)d_out;
  float* out_w = out_adj + (size_t)kHalf;

  hipLaunchKernelGGL(mlp_probs_kernel, dim3(512), dim3(256), 0, stream,
                     nodes, num_nodes, W1, b1, W2, b2, out_w);
  hipLaunchKernelGGL(edge_sample_kernel, dim3(kHalf / 1024), dim3(256), 0, stream,
                     weights, num_nodes, out_adj, out_w);
}

// Round 8
// 72.782 us; speedup vs baseline: 1.2829x; 1.2829x over previous
//
#include <hip/hip_runtime.h>
#include <stdint.h>

namespace {

constexpr int kB = 16;
constexpr int kN = 1024;
constexpr int kF = 128;
constexpr int kHalf = kB * kN * kN;   // 16,777,216 == B*N*N; noise array is [2, B, N, N]
constexpr int kNumBlocks = kHalf / 1024;  // 16384 pass-1 blocks (256 thr x 4 elem)

__device__ __forceinline__ uint32_t rotl32(uint32_t x, int r) {
  return (x << r) | (x >> (32 - r));
}

// JAX threefry2x32 with key = (0, 42)  [jax.random.key(42)]
__device__ __forceinline__ void tf2x32(uint32_t x0, uint32_t x1,
                                       uint32_t& o0, uint32_t& o1) {
  constexpr uint32_t ks0 = 0u;
  constexpr uint32_t ks1 = 42u;
  constexpr uint32_t ks2 = 0u ^ 42u ^ 0x1BD11BDAu;
  x0 += ks0; x1 += ks1;
#define TFR(r) { x0 += x1; x1 = rotl32(x1, (r)); x1 ^= x0; }
  TFR(13) TFR(15) TFR(26) TFR(6)
  x0 += ks1; x1 += ks2 + 1u;
  TFR(17) TFR(29) TFR(16) TFR(24)
  x0 += ks2; x1 += ks0 + 2u;
  TFR(13) TFR(15) TFR(26) TFR(6)
  x0 += ks0; x1 += ks1 + 3u;
  TFR(17) TFR(29) TFR(16) TFR(24)
  x0 += ks1; x1 += ks2 + 4u;
  TFR(13) TFR(15) TFR(26) TFR(6)
  x0 += ks2; x1 += ks0 + 5u;
#undef TFR
  o0 = x0; o1 = x1;
}

// partitionable mode: bits[idx] = o0 ^ o1 of threefry(key, (idx>>32, idx&0xffffffff))
__device__ __forceinline__ uint32_t random_bits_part(uint32_t idx) {
  uint32_t o0, o1;
  tf2x32(0u, idx, o0, o1);
  return o0 ^ o1;
}

// jax.random.uniform conversion: f in [0,1) from top-23 mantissa bits;
// u = max(1e-10f, f + 1e-10f)   ((maxval-minval) rounds to exactly 1.0f)
__device__ __forceinline__ float bits_to_uniform(uint32_t bits) {
  float f = __uint_as_float((bits >> 9) | 0x3F800000u) - 1.0f;
  return fmaxf(1e-10f, f + 1e-10f);
}

// Full decision for one element (R7-validated: passed absmax 0.0):
// fast v_log path with OCML-exact fallback in the |D|<=0.01 ambiguity band.
__device__ __forceinline__ float decide_elem(uint32_t q, float c0, float c1) {
  const float u0 = bits_to_uniform(random_bits_part(q));
  const float u1 = bits_to_uniform(random_bits_part(q + (uint32_t)kHalf));
  const float lf0 = __log2f(u0);
  const float lf1 = __log2f(u1);
  const float D = c0 * lf1 - c1 * lf0;   // > 0 -> class 1
  float r = (D > 0.0f) ? 1.0f : 0.0f;
  if (fabsf(D) <= 0.01f) {
    const float L0 = -logf(u0);          // OCML, faithful
    const float L1 = -logf(u1);
    r = (c1 * L0 > c0 * L1) ? 1.0f : 0.0f;
  }
  return r;
}

// ---------------------------------------------------------------------------
// Kernel 1: probs[b,i] = clip(sigmoid(leaky_relu([left_b, nodes_bi] @ W1 + b1) @ W2 + b2))
// Tiled f32 GEMM: 512 blocks x 256 threads, each block does 32 rows (one b).
// Result scattered into out_w[(b*N + i)*N + nn_b] (read-before-write staging).
// ---------------------------------------------------------------------------
__global__ __launch_bounds__(256) void mlp_probs_kernel(
    const float* __restrict__ nodes, const int* __restrict__ num_nodes,
    const float* __restrict__ W1, const float* __restrict__ b1,
    const float* __restrict__ W2, const float* __restrict__ b2,
    float* __restrict__ out_w) {
  __shared__ float xs[32][256];   // 32 KiB: per-row input [left(128) | nodes_row(128)]
  __shared__ float bt[16][128];   // 8 KiB: W1 K-tile
  __shared__ float hs[32][128];   // 16 KiB: hidden activations
  __shared__ float h2[32][8];     // 1 KiB: second-layer partials

  const int blk = blockIdx.x;      // 512 blocks = 16 b * 32 row-chunks
  const int b = blk >> 5;
  const int i0 = (blk & 31) * 32;
  const int t = threadIdx.x;
  const int nn = num_nodes[b];
  const float* nb = nodes + (size_t)b * kN * kF;
  const float* leftp = nb + (size_t)nn * kF;

  // stage X tile [32 rows][256]
  for (int chunk = 0; chunk < 16; ++chunk) {
    int idx = chunk * 256 + t;   // 0..4095
    int r = idx >> 7;            // 0..31
    int c = idx & 127;
    xs[r][c] = leftp[c];
    xs[r][128 + c] = nb[(size_t)(i0 + r) * kF + c];
  }

  const int tx = t & 31;   // 4 cols each -> 128 cols
  const int ty = t >> 5;   // 4 rows each -> 32 rows
  float acc[4][4];
#pragma unroll
  for (int rr = 0; rr < 4; ++rr)
#pragma unroll
    for (int cc = 0; cc < 4; ++cc) acc[rr][cc] = 0.0f;

  for (int k0 = 0; k0 < 256; k0 += 16) {
    __syncthreads();  // xs ready (first iter) / bt consumers done (later iters)
#pragma unroll
    for (int qq = 0; qq < 8; ++qq) {
      int idx = qq * 256 + t;    // 0..2047
      int kk = idx >> 7;         // 0..15
      int c = idx & 127;
      bt[kk][c] = W1[(size_t)(k0 + kk) * kF + c];
    }
    __syncthreads();
#pragma unroll
    for (int kk = 0; kk < 16; ++kk) {
      float bv0 = bt[kk][4 * tx + 0];
      float bv1 = bt[kk][4 * tx + 1];
      float bv2 = bt[kk][4 * tx + 2];
      float bv3 = bt[kk][4 * tx + 3];
#pragma unroll
      for (int rr = 0; rr < 4; ++rr) {
        float xv = xs[4 * ty + rr][k0 + kk];
        acc[rr][0] = fmaf(xv, bv0, acc[rr][0]);
        acc[rr][1] = fmaf(xv, bv1, acc[rr][1]);
        acc[rr][2] = fmaf(xv, bv2, acc[rr][2]);
        acc[rr][3] = fmaf(xv, bv3, acc[rr][3]);
      }
    }
  }

  // bias + leaky_relu(0.01) -> hs
#pragma unroll
  for (int rr = 0; rr < 4; ++rr)
#pragma unroll
    for (int cc = 0; cc < 4; ++cc) {
      float v = acc[rr][cc] + b1[4 * tx + cc];
      hs[4 * ty + rr][4 * tx + cc] = (v >= 0.0f) ? v : 0.01f * v;
    }
  __syncthreads();

  // second layer: z = hs @ W2 + b2 ; 8 partial sums of 16 per row
  {
    const int r = t >> 3;  // 0..31
    const int q = t & 7;   // 0..7
    float s = 0.0f;
#pragma unroll
    for (int j = 0; j < 16; ++j) {
      int k = q * 16 + j;
      s = fmaf(hs[r][k], W2[k], s);
    }
    h2[r][q] = s;
  }
  __syncthreads();

  if (t < 32) {
    float z = 0.0f;
#pragma unroll
    for (int q = 0; q < 8; ++q) z += h2[t][q];
    z += b2[0];
    double p = 1.0 / (1.0 + exp(-(double)z));  // high-accuracy sigmoid
    float pc = fminf(fmaxf((float)p, 0.001f), 0.999f);
    // stage into out_w at [b][i][nn]; kernel 2's owning thread reads it back
    out_w[(size_t)((b << 10) + i0 + t) * kN + nn] = pc;
  }
}

// ---------------------------------------------------------------------------
// Pass 1: per element, hash ONLY u1. Certain-class0 screen:
//   exact chain gives class1 iff c1*L0 > c0*L1, and L0 <= -logf(1e-10) = 23.025851.
//   So if c0 * L1_lowerbound >= c1 * 23.0262  ->  class0 GUARANTEED.
//   L1_lowerbound = 0.693078 * l1v  (l1v = -__log2f(u1); 0.693078 < ln2 by 1e-4
//   relative, absorbing v_log + OCML-logf error by a >800-ulp margin).
// Survivors (~2.3%: w=0 boundary cases + selected column) are compacted into
// per-block segments of d_ws (LDS-atomic compaction; no global atomics) and
// resolved densely by pass 2 with the R7-validated full path.
// ---------------------------------------------------------------------------
__global__ __launch_bounds__(256) void edge_screen_kernel(
    const float* __restrict__ weights, const int* __restrict__ num_nodes,
    float* __restrict__ out_adj, float* __restrict__ out_w,
    uint32_t* __restrict__ counts, uint32_t* __restrict__ list,
    uint32_t cap_pb) {
  __shared__ uint32_t s_cnt;
  if (threadIdx.x == 0) s_cnt = 0;
  __syncthreads();

  const int tid = blockIdx.x * 256 + threadIdx.x;
  const int q0 = tid * 4;                 // grid sized exactly: q0 < kHalf
  const int b = q0 >> 20;                 // N*N = 2^20
  const int i = (q0 >> 10) & 1023;
  const int j0 = q0 & 1023;
  const int nn = num_nodes[b];
  const bool rowsel = (i < nn);
  const int rowbase = q0 - j0;            // (b*N + i)*N

  // p staged by kernel 1 at out_w[rowbase + nn]; only the thread whose quad
  // contains column nn needs it (it reads before it overwrites - same thread).
  float pv = 0.0f;
  if (rowsel && nn >= j0 && nn < j0 + 4) pv = out_w[rowbase + nn];

  const float4 wq = *reinterpret_cast<const float4*>(weights + q0);
  float wvals[4] = {wq.x, wq.y, wq.z, wq.w};
  float oa[4], ow[4];
  uint32_t* blist = list + (size_t)blockIdx.x * cap_pb;

#pragma unroll
  for (int ee = 0; ee < 4; ++ee) {
    const int j = j0 + ee;
    const float w = (rowsel && (j == nn)) ? pv : wvals[ee];
    // clip([1-w, w], 0.001, 0.999)
    const float c1 = fminf(fmaxf(w, 0.001f), 0.999f);
    const float c0 = fminf(fmaxf(1.0f - w, 0.001f), 0.999f);

    const float u1 = bits_to_uniform(
        random_bits_part((uint32_t)(q0 + ee) + (uint32_t)kHalf));
    const float l1 = -__log2f(u1);

    oa[ee] = 0.0f;
    ow[ee] = w;
    const bool certain0 = (0.693078f * (c0 * l1) >= 23.0262f * c1);
    if (!certain0) {
      uint32_t idx = atomicAdd(&s_cnt, 1u);
      if (idx < cap_pb) {
        blist[idx] = (uint32_t)(q0 + ee);
      } else {
        // overflow / no-workspace fallback: decide inline (rare or never)
        oa[ee] = decide_elem((uint32_t)(q0 + ee), c0, c1);
      }
    }
  }

  *reinterpret_cast<float4*>(out_adj + q0) = make_float4(oa[0], oa[1], oa[2], oa[3]);
  *reinterpret_cast<float4*>(out_w + q0) = make_float4(ow[0], ow[1], ow[2], ow[3]);

  __syncthreads();
  if (threadIdx.x == 0 && cap_pb != 0) {
    counts[blockIdx.x] = (s_cnt < cap_pb) ? s_cnt : cap_pb;
  }
}

// ---------------------------------------------------------------------------
// Pass 2: resolve compacted survivors (dense, no divergence waste).
// w for entry q is just out_w[q] (pass 1 already wrote the final w there).
// ---------------------------------------------------------------------------
__global__ __launch_bounds__(64) void edge_resolve_kernel(
    float* __restrict__ out_adj, const float* __restrict__ out_w,
    const uint32_t* __restrict__ counts, const uint32_t* __restrict__ list,
    uint32_t cap_pb) {
  const uint32_t blk = blockIdx.x;
  const uint32_t n = counts[blk];          // already clamped to cap_pb
  const uint32_t* blist = list + (size_t)blk * cap_pb;
  for (uint32_t k = threadIdx.x; k < n; k += 64) {
    const uint32_t q = blist[k];
    const float w = out_w[q];
    const float c1 = fminf(fmaxf(w, 0.001f), 0.999f);
    const float c0 = fminf(fmaxf(1.0f - w, 0.001f), 0.999f);
    out_adj[q] = decide_elem(q, c0, c1);
  }
}

}  // namespace

extern "C" void kernel_launch(void* const* d_in, const int* in_sizes, int n_in,
                              void* d_out, int out_size, void* d_ws, size_t ws_size,
                              hipStream_t stream) {
  (void)in_sizes; (void)n_in; (void)out_size;
  const float* nodes = (const float*)d_in[0];
  // d_in[1] = adj (unused by reference)
  const float* weights = (const float*)d_in[2];
  const int* num_nodes = (const int*)d_in[3];
  // d_in[4] = B scalar (compile-time constant here)
  const float* W1 = (const float*)d_in[5];
  const float* b1 = (const float*)d_in[6];
  const float* W2 = (const float*)d_in[7];
  const float* b2 = (const float*)d_in[8];

  float* out_adj = (float*)d_out;
  float* out_w = out_adj + (size_t)kHalf;

  // workspace layout: [counts: 16384 u32][list: 16384 * cap_pb u32]
  const size_t counts_bytes = (size_t)kNumBlocks * sizeof(uint32_t);
  uint32_t cap_pb = 0;
  if (ws_size > counts_bytes) {
    size_t per_block = (ws_size - counts_bytes) / sizeof(uint32_t) / kNumBlocks;
    cap_pb = (uint32_t)((per_block > 1024) ? 1024 : per_block);
  }
  uint32_t* counts = (uint32_t*)d_ws;
  uint32_t* list = (uint32_t*)((char*)d_ws + counts_bytes);

  hipLaunchKernelGGL(mlp_probs_kernel, dim3(512), dim3(256), 0, stream,
                     nodes, num_nodes, W1, b1, W2, b2, out_w);
  hipLaunchKernelGGL(edge_screen_kernel, dim3(kNumBlocks), dim3(256), 0, stream,
                     weights, num_nodes, out_adj, out_w, counts, list, cap_pb);
  if (cap_pb != 0) {
    hipLaunchKernelGGL(edge_resolve_kernel, dim3(kNumBlocks), dim3(64), 0, stream,
                       out_adj, out_w, counts, list, cap_pb);
  }
}

// Round 11
// 62.004 us; speedup vs baseline: 1.5059x; 1.1738x over previous
//
#include <hip/hip_runtime.h>
#include <stdint.h>

namespace {

constexpr int kB = 16;
constexpr int kN = 1024;
constexpr int kF = 128;
constexpr int kHalf = kB * kN * kN;   // 16,777,216 == B*N*N; noise array is [2, B, N, N]

__device__ __forceinline__ uint32_t rotl32(uint32_t x, int r) {
  return (x << r) | (x >> (32 - r));
}

// JAX threefry2x32 with key = (0, 42)  [jax.random.key(42)]
__device__ __forceinline__ void tf2x32(uint32_t x0, uint32_t x1,
                                       uint32_t& o0, uint32_t& o1) {
  constexpr uint32_t ks0 = 0u;
  constexpr uint32_t ks1 = 42u;
  constexpr uint32_t ks2 = 0u ^ 42u ^ 0x1BD11BDAu;
  x0 += ks0; x1 += ks1;
#define TFR(r) { x0 += x1; x1 = rotl32(x1, (r)); x1 ^= x0; }
  TFR(13) TFR(15) TFR(26) TFR(6)
  x0 += ks1; x1 += ks2 + 1u;
  TFR(17) TFR(29) TFR(16) TFR(24)
  x0 += ks2; x1 += ks0 + 2u;
  TFR(13) TFR(15) TFR(26) TFR(6)
  x0 += ks0; x1 += ks1 + 3u;
  TFR(17) TFR(29) TFR(16) TFR(24)
  x0 += ks1; x1 += ks2 + 4u;
  TFR(13) TFR(15) TFR(26) TFR(6)
  x0 += ks2; x1 += ks0 + 5u;
#undef TFR
  o0 = x0; o1 = x1;
}

// partitionable mode: bits[idx] = o0 ^ o1 of threefry(key, (idx>>32, idx&0xffffffff))
__device__ __forceinline__ uint32_t random_bits_part(uint32_t idx) {
  uint32_t o0, o1;
  tf2x32(0u, idx, o0, o1);
  return o0 ^ o1;
}

// jax.random.uniform conversion: f in [0,1) from top-23 mantissa bits;
// u = max(1e-10f, f + 1e-10f)   ((maxval-minval) rounds to exactly 1.0f)
__device__ __forceinline__ float bits_to_uniform(uint32_t bits) {
  float f = __uint_as_float((bits >> 9) | 0x3F800000u) - 1.0f;
  return fmaxf(1e-10f, f + 1e-10f);
}

// Full decision for one element (R7-validated: passed absmax 0.0):
// fast v_log path with OCML-exact fallback in the |D|<=0.01 ambiguity band.
__device__ __forceinline__ float decide_elem(uint32_t q, float c0, float c1) {
  const float u0 = bits_to_uniform(random_bits_part(q));
  const float u1 = bits_to_uniform(random_bits_part(q + (uint32_t)kHalf));
  const float lf0 = __log2f(u0);
  const float lf1 = __log2f(u1);
  const float D = c0 * lf1 - c1 * lf0;   // > 0 -> class 1
  float r = (D > 0.0f) ? 1.0f : 0.0f;
  if (fabsf(D) <= 0.01f) {
    const float L0 = -logf(u0);          // OCML, faithful
    const float L1 = -logf(u1);
    r = (c1 * L0 > c0 * L1) ? 1.0f : 0.0f;
  }
  return r;
}

// ---------------------------------------------------------------------------
// Kernel 1: probs[b,i] = clip(sigmoid(leaky_relu([left_b, nodes_bi] @ W1 + b1) @ W2 + b2))
// Tiled f32 GEMM: 512 blocks x 256 threads, each block does 32 rows (one b).
// Result scattered into out_w[(b*N + i)*N + nn_b] (read-before-write staging).
// Blocks whose 32 rows are all >= num_nodes[b] produce only unused probs ->
// uniform early exit (screen kernel overwrites their staging slots anyway).
// ---------------------------------------------------------------------------
__global__ __launch_bounds__(256) void mlp_probs_kernel(
    const float* __restrict__ nodes, const int* __restrict__ num_nodes,
    const float* __restrict__ W1, const float* __restrict__ b1,
    const float* __restrict__ W2, const float* __restrict__ b2,
    float* __restrict__ out_w) {
  __shared__ float xs[32][256];   // 32 KiB: per-row input [left(128) | nodes_row(128)]
  __shared__ float bt[16][128];   // 8 KiB: W1 K-tile
  __shared__ float hs[32][128];   // 16 KiB: hidden activations
  __shared__ float h2[32][8];     // 1 KiB: second-layer partials

  const int blk = blockIdx.x;      // 512 blocks = 16 b * 32 row-chunks
  const int b = blk >> 5;
  const int i0 = (blk & 31) * 32;
  const int t = threadIdx.x;
  const int nn = num_nodes[b];
  if (i0 >= nn) return;            // uniform: no row in this chunk has i < nn
  const float* nb = nodes + (size_t)b * kN * kF;
  const float* leftp = nb + (size_t)nn * kF;

  // stage X tile [32 rows][256]
  for (int chunk = 0; chunk < 16; ++chunk) {
    int idx = chunk * 256 + t;   // 0..4095
    int r = idx >> 7;            // 0..31
    int c = idx & 127;
    xs[r][c] = leftp[c];
    xs[r][128 + c] = nb[(size_t)(i0 + r) * kF + c];
  }

  const int tx = t & 31;   // 4 cols each -> 128 cols
  const int ty = t >> 5;   // 4 rows each -> 32 rows
  float acc[4][4];
#pragma unroll
  for (int rr = 0; rr < 4; ++rr)
#pragma unroll
    for (int cc = 0; cc < 4; ++cc) acc[rr][cc] = 0.0f;

  for (int k0 = 0; k0 < 256; k0 += 16) {
    __syncthreads();  // xs ready (first iter) / bt consumers done (later iters)
#pragma unroll
    for (int qq = 0; qq < 8; ++qq) {
      int idx = qq * 256 + t;    // 0..2047
      int kk = idx >> 7;         // 0..15
      int c = idx & 127;
      bt[kk][c] = W1[(size_t)(k0 + kk) * kF + c];
    }
    __syncthreads();
#pragma unroll
    for (int kk = 0; kk < 16; ++kk) {
      float bv0 = bt[kk][4 * tx + 0];
      float bv1 = bt[kk][4 * tx + 1];
      float bv2 = bt[kk][4 * tx + 2];
      float bv3 = bt[kk][4 * tx + 3];
#pragma unroll
      for (int rr = 0; rr < 4; ++rr) {
        float xv = xs[4 * ty + rr][k0 + kk];
        acc[rr][0] = fmaf(xv, bv0, acc[rr][0]);
        acc[rr][1] = fmaf(xv, bv1, acc[rr][1]);
        acc[rr][2] = fmaf(xv, bv2, acc[rr][2]);
        acc[rr][3] = fmaf(xv, bv3, acc[rr][3]);
      }
    }
  }

  // bias + leaky_relu(0.01) -> hs
#pragma unroll
  for (int rr = 0; rr < 4; ++rr)
#pragma unroll
    for (int cc = 0; cc < 4; ++cc) {
      float v = acc[rr][cc] + b1[4 * tx + cc];
      hs[4 * ty + rr][4 * tx + cc] = (v >= 0.0f) ? v : 0.01f * v;
    }
  __syncthreads();

  // second layer: z = hs @ W2 + b2 ; 8 partial sums of 16 per row
  {
    const int r = t >> 3;  // 0..31
    const int q = t & 7;   // 0..7
    float s = 0.0f;
#pragma unroll
    for (int j = 0; j < 16; ++j) {
      int k = q * 16 + j;
      s = fmaf(hs[r][k], W2[k], s);
    }
    h2[r][q] = s;
  }
  __syncthreads();

  if (t < 32) {
    float z = 0.0f;
#pragma unroll
    for (int q = 0; q < 8; ++q) z += h2[t][q];
    z += b2[0];
    double p = 1.0 / (1.0 + exp(-(double)z));  // high-accuracy sigmoid
    float pc = fminf(fmaxf((float)p, 0.001f), 0.999f);
    // stage into out_w at [b][i][nn]; screen kernel's owning thread reads it back
    out_w[(size_t)((b << 10) + i0 + t) * kN + nn] = pc;
  }
}

// ---------------------------------------------------------------------------
// Kernel 2 (fused screen+resolve): per (b,i,j), 4 elements per thread.
//
// Hot path: ONE threefry hash (u1 only) + integer mantissa compare.
// Soundness of the w==0 certain-class0 screen (vs the R6 exact chain AND XLA):
//   w==0 -> c1 = 0.001f, c0 = 0.999f exactly.
//   mant <= 8190000  ==>  u1 <= 8190001/2^23 = 0.9763242  (the +1e-10 in the
//   uniform conversion rounds away at this magnitude; smaller u1 only helps)
//   ==>  L1 = -log(u1) >= 0.0239609  ==>  c0*L1 >= 0.0239369.
//   L0 <= -log(1e-10) = 23.0258509  ==>  c1*L0 <= 0.0230259.
//   Margin 9.1e-4 (~3.8% rel) vs float-eval jitter <= ~1e-6  ==> class0
//   guaranteed (strict-> comparison; ties -> class0 on all paths).
// Everything else (w != 0, i.e. the selected column, or mant > threshold)
// is compacted to LDS (worst case 1024/block -- cannot overflow) and resolved
// densely post-barrier with the R7-validated decide_elem. Class-1 survivors
// patch out_adj[q]=1.0 (float4 zeros landed pre-barrier; __syncthreads drains
// vmcnt(0), so the patch is ordered after them in L2).
// ---------------------------------------------------------------------------
__global__ __launch_bounds__(256) void edge_screen_kernel(
    const float* __restrict__ weights, const int* __restrict__ num_nodes,
    float* __restrict__ out_adj, float* __restrict__ out_w) {
  __shared__ uint32_t s_cnt;
  __shared__ uint32_t s_q[1024];
  __shared__ float s_w[1024];
  if (threadIdx.x == 0) s_cnt = 0;
  __syncthreads();

  const int tid = blockIdx.x * 256 + threadIdx.x;
  const int q0 = tid * 4;                 // grid sized exactly: q0 < kHalf
  const int b = q0 >> 20;                 // N*N = 2^20
  const int i = (q0 >> 10) & 1023;
  const int j0 = q0 & 1023;
  const int nn = num_nodes[b];
  const bool rowsel = (i < nn);
  const int rowbase = q0 - j0;            // (b*N + i)*N

  // p staged by kernel 1 at out_w[rowbase + nn]; only the thread whose quad
  // contains column nn needs it (it reads before it overwrites - same thread).
  float pv = 0.0f;
  if (rowsel && nn >= j0 && nn < j0 + 4) pv = out_w[rowbase + nn];

  const float4 wq = *reinterpret_cast<const float4*>(weights + q0);
  float wvals[4] = {wq.x, wq.y, wq.z, wq.w};
  float oa[4], ow[4];

  constexpr uint32_t kMant0 = 8190000u;   // see soundness proof above

#pragma unroll
  for (int ee = 0; ee < 4; ++ee) {
    const int j = j0 + ee;
    const float w = (rowsel && (j == nn)) ? pv : wvals[ee];
    const uint32_t mant =
        random_bits_part((uint32_t)(q0 + ee) + (uint32_t)kHalf) >> 9;
    oa[ee] = 0.0f;
    ow[ee] = w;
    if ((w != 0.0f) || (mant > kMant0)) {
      uint32_t k = atomicAdd(&s_cnt, 1u);
      s_q[k] = (uint32_t)(q0 + ee);
      s_w[k] = w;
    }
  }

  *reinterpret_cast<float4*>(out_adj + q0) = make_float4(oa[0], oa[1], oa[2], oa[3]);
  *reinterpret_cast<float4*>(out_w + q0) = make_float4(ow[0], ow[1], ow[2], ow[3]);

  __syncthreads();   // drains the stores above; publishes s_cnt/s_q/s_w

  const uint32_t n = s_cnt;
  for (uint32_t k = threadIdx.x; k < n; k += 256) {
    const uint32_t q = s_q[k];
    const float w = s_w[k];
    const float c1 = fminf(fmaxf(w, 0.001f), 0.999f);
    const float c0 = fminf(fmaxf(1.0f - w, 0.001f), 0.999f);
    if (decide_elem(q, c0, c1) > 0.5f) out_adj[q] = 1.0f;
  }
}

}  // namespace

extern "C" void kernel_launch(void* const* d_in, const int* in_sizes, int n_in,
                              void* d_out, int out_size, void* d_ws, size_t ws_size,
                              hipStream_t stream) {
  (void)in_sizes; (void)n_in; (void)out_size; (void)d_ws; (void)ws_size;
  const float* nodes = (const float*)d_in[0];
  // d_in[1] = adj (unused by reference)
  const float* weights = (const float*)d_in[2];
  const int* num_nodes = (const int*)d_in[3];
  // d_in[4] = B scalar (compile-time constant here)
  const float* W1 = (const float*)d_in[5];
  const float* b1 = (const float*)d_in[6];
  const float* W2 = (const float*)d_in[7];
  const float* b2 = (const float*)d_in[8];

  float* out_adj = (float*)d_out;
  float* out_w = out_adj + (size_t)kHalf;

  hipLaunchKernelGGL(mlp_probs_kernel, dim3(512), dim3(256), 0, stream,
                     nodes, num_nodes, W1, b1, W2, b2, out_w);
  hipLaunchKernelGGL(edge_screen_kernel, dim3(kHalf / 1024), dim3(256), 0, stream,
                     weights, num_nodes, out_adj, out_w);
}

// Round 13
// 59.989 us; speedup vs baseline: 1.5565x; 1.0336x over previous
//
#include <hip/hip_runtime.h>
#include <stdint.h>

namespace {

constexpr int kB = 16;
constexpr int kN = 1024;
constexpr int kF = 128;
constexpr int kHalf = kB * kN * kN;   // 16,777,216 == B*N*N; noise array is [2, B, N, N]
constexpr int kElems = 8;             // elements per thread in the screen kernel
constexpr int kScreenBlocks = kHalf / (256 * kElems);  // 8192

typedef float f32x4 __attribute__((ext_vector_type(4)));  // native vec for nontemporal

__device__ __forceinline__ uint32_t rotl32(uint32_t x, int r) {
  // v_alignbit_b32 x,x,(32-r) == rotr(x,32-r) == rotl(x,r): single instruction.
  return __builtin_amdgcn_alignbit(x, x, 32 - r);
}

// JAX threefry2x32 with key = (0, 42)  [jax.random.key(42)]
__device__ __forceinline__ void tf2x32(uint32_t x0, uint32_t x1,
                                       uint32_t& o0, uint32_t& o1) {
  constexpr uint32_t ks0 = 0u;
  constexpr uint32_t ks1 = 42u;
  constexpr uint32_t ks2 = 0u ^ 42u ^ 0x1BD11BDAu;
  x0 += ks0; x1 += ks1;
#define TFR(r) { x0 += x1; x1 = rotl32(x1, (r)); x1 ^= x0; }
  TFR(13) TFR(15) TFR(26) TFR(6)
  x0 += ks1; x1 += ks2 + 1u;
  TFR(17) TFR(29) TFR(16) TFR(24)
  x0 += ks2; x1 += ks0 + 2u;
  TFR(13) TFR(15) TFR(26) TFR(6)
  x0 += ks0; x1 += ks1 + 3u;
  TFR(17) TFR(29) TFR(16) TFR(24)
  x0 += ks1; x1 += ks2 + 4u;
  TFR(13) TFR(15) TFR(26) TFR(6)
  x0 += ks2; x1 += ks0 + 5u;
#undef TFR
  o0 = x0; o1 = x1;
}

// partitionable mode: bits[idx] = o0 ^ o1 of threefry(key, (idx>>32, idx&0xffffffff))
__device__ __forceinline__ uint32_t random_bits_part(uint32_t idx) {
  uint32_t o0, o1;
  tf2x32(0u, idx, o0, o1);
  return o0 ^ o1;
}

// jax.random.uniform conversion: f in [0,1) from top-23 mantissa bits;
// u = max(1e-10f, f + 1e-10f)   ((maxval-minval) rounds to exactly 1.0f)
__device__ __forceinline__ float bits_to_uniform(uint32_t bits) {
  float f = __uint_as_float((bits >> 9) | 0x3F800000u) - 1.0f;
  return fmaxf(1e-10f, f + 1e-10f);
}

// Full decision for one element (R7-validated: passed absmax 0.0):
// fast v_log path with OCML-exact fallback in the |D|<=0.01 ambiguity band.
__device__ __forceinline__ float decide_elem(uint32_t q, float c0, float c1) {
  const float u0 = bits_to_uniform(random_bits_part(q));
  const float u1 = bits_to_uniform(random_bits_part(q + (uint32_t)kHalf));
  const float lf0 = __log2f(u0);
  const float lf1 = __log2f(u1);
  const float D = c0 * lf1 - c1 * lf0;   // > 0 -> class 1
  float r = (D > 0.0f) ? 1.0f : 0.0f;
  if (fabsf(D) <= 0.01f) {
    const float L0 = -logf(u0);          // OCML, faithful
    const float L1 = -logf(u1);
    r = (c1 * L0 > c0 * L1) ? 1.0f : 0.0f;
  }
  return r;
}

// ---------------------------------------------------------------------------
// Kernel 1: probs[b,i] = clip(sigmoid(leaky_relu([left_b, nodes_bi] @ W1 + b1) @ W2 + b2))
// Tiled f32 GEMM: 512 blocks x 256 threads, each block does 32 rows (one b).
// Result scattered into out_w[(b*N + i)*N + nn_b] (read-before-write staging).
// Blocks whose 32 rows are all >= num_nodes[b] produce only unused probs ->
// uniform early exit (screen kernel overwrites their staging slots anyway).
// ---------------------------------------------------------------------------
__global__ __launch_bounds__(256) void mlp_probs_kernel(
    const float* __restrict__ nodes, const int* __restrict__ num_nodes,
    const float* __restrict__ W1, const float* __restrict__ b1,
    const float* __restrict__ W2, const float* __restrict__ b2,
    float* __restrict__ out_w) {
  __shared__ float xs[32][256];   // 32 KiB: per-row input [left(128) | nodes_row(128)]
  __shared__ float bt[16][128];   // 8 KiB: W1 K-tile
  __shared__ float hs[32][128];   // 16 KiB: hidden activations
  __shared__ float h2[32][8];     // 1 KiB: second-layer partials

  const int blk = blockIdx.x;      // 512 blocks = 16 b * 32 row-chunks
  const int b = blk >> 5;
  const int i0 = (blk & 31) * 32;
  const int t = threadIdx.x;
  const int nn = num_nodes[b];
  if (i0 >= nn) return;            // uniform: no row in this chunk has i < nn
  const float* nb = nodes + (size_t)b * kN * kF;
  const float* leftp = nb + (size_t)nn * kF;

  // stage X tile [32 rows][256]
  for (int chunk = 0; chunk < 16; ++chunk) {
    int idx = chunk * 256 + t;   // 0..4095
    int r = idx >> 7;            // 0..31
    int c = idx & 127;
    xs[r][c] = leftp[c];
    xs[r][128 + c] = nb[(size_t)(i0 + r) * kF + c];
  }

  const int tx = t & 31;   // 4 cols each -> 128 cols
  const int ty = t >> 5;   // 4 rows each -> 32 rows
  float acc[4][4];
#pragma unroll
  for (int rr = 0; rr < 4; ++rr)
#pragma unroll
    for (int cc = 0; cc < 4; ++cc) acc[rr][cc] = 0.0f;

  for (int k0 = 0; k0 < 256; k0 += 16) {
    __syncthreads();  // xs ready (first iter) / bt consumers done (later iters)
#pragma unroll
    for (int qq = 0; qq < 8; ++qq) {
      int idx = qq * 256 + t;    // 0..2047
      int kk = idx >> 7;         // 0..15
      int c = idx & 127;
      bt[kk][c] = W1[(size_t)(k0 + kk) * kF + c];
    }
    __syncthreads();
#pragma unroll
    for (int kk = 0; kk < 16; ++kk) {
      float bv0 = bt[kk][4 * tx + 0];
      float bv1 = bt[kk][4 * tx + 1];
      float bv2 = bt[kk][4 * tx + 2];
      float bv3 = bt[kk][4 * tx + 3];
#pragma unroll
      for (int rr = 0; rr < 4; ++rr) {
        float xv = xs[4 * ty + rr][k0 + kk];
        acc[rr][0] = fmaf(xv, bv0, acc[rr][0]);
        acc[rr][1] = fmaf(xv, bv1, acc[rr][1]);
        acc[rr][2] = fmaf(xv, bv2, acc[rr][2]);
        acc[rr][3] = fmaf(xv, bv3, acc[rr][3]);
      }
    }
  }

  // bias + leaky_relu(0.01) -> hs
#pragma unroll
  for (int rr = 0; rr < 4; ++rr)
#pragma unroll
    for (int cc = 0; cc < 4; ++cc) {
      float v = acc[rr][cc] + b1[4 * tx + cc];
      hs[4 * ty + rr][4 * tx + cc] = (v >= 0.0f) ? v : 0.01f * v;
    }
  __syncthreads();

  // second layer: z = hs @ W2 + b2 ; 8 partial sums of 16 per row
  {
    const int r = t >> 3;  // 0..31
    const int q = t & 7;   // 0..7
    float s = 0.0f;
#pragma unroll
    for (int j = 0; j < 16; ++j) {
      int k = q * 16 + j;
      s = fmaf(hs[r][k], W2[k], s);
    }
    h2[r][q] = s;
  }
  __syncthreads();

  if (t < 32) {
    float z = 0.0f;
#pragma unroll
    for (int q = 0; q < 8; ++q) z += h2[t][q];
    z += b2[0];
    double p = 1.0 / (1.0 + exp(-(double)z));  // high-accuracy sigmoid
    float pc = fminf(fmaxf((float)p, 0.001f), 0.999f);
    // stage into out_w at [b][i][nn]; screen kernel's owning thread reads it back
    out_w[(size_t)((b << 10) + i0 + t) * kN + nn] = pc;
  }
}

// ---------------------------------------------------------------------------
// Kernel 2 (fused screen+resolve): per (b,i,j), 8 elements per thread.
//
// Hot path: ONE threefry hash (u1 only) + ONE raw-bits integer compare.
// Soundness of the w==0 certain-class0 screen (vs the R6 exact chain AND XLA):
//   w==0 -> c1 = 0.001f, c0 = 0.999f exactly.
//   bits <= (8190000<<9)|511  <==>  mant = bits>>9 <= 8190000
//   ==>  u1 <= 8190001/2^23 = 0.9763242  (the +1e-10 in the uniform conversion
//   rounds away at this magnitude; smaller u1 only helps)
//   ==>  L1 = -log(u1) >= 0.0239609  ==>  c0*L1 >= 0.0239369.
//   L0 <= -log(1e-10) = 23.0258509  ==>  c1*L0 <= 0.0230259.
//   Margin 9.1e-4 (~3.8% rel) vs float-eval jitter <= ~1e-6  ==> class0
//   guaranteed (strict-> comparison; ties -> class0 on all paths).
// Everything else (w != 0, i.e. the selected column, or bits > threshold)
// is compacted to LDS (worst case 2048/block -- cannot overflow) and resolved
// densely post-barrier with the R7-validated decide_elem. Class-1 survivors
// patch out_adj[q]=1.0 (zeros landed pre-barrier; __syncthreads drains
// vmcnt(0), so the patch is ordered after them in L2). out_w is never patched
// -> nontemporal stores (streaming hint, keeps L2 for weights).
// ---------------------------------------------------------------------------
__global__ __launch_bounds__(256) void edge_screen_kernel(
    const float* __restrict__ weights, const int* __restrict__ num_nodes,
    float* __restrict__ out_adj, float* __restrict__ out_w) {
  __shared__ uint32_t s_cnt;
  __shared__ uint32_t s_q[256 * kElems];
  __shared__ float s_w[256 * kElems];
  if (threadIdx.x == 0) s_cnt = 0;
  __syncthreads();

  const int tid = blockIdx.x * 256 + threadIdx.x;
  const int q0 = tid * kElems;            // grid sized exactly: q0 < kHalf
  const int b = q0 >> 20;                 // N*N = 2^20
  const int i = (q0 >> 10) & 1023;
  const int j0 = q0 & 1023;               // kElems | 1024: all 8 in one row
  const int nn = num_nodes[b];
  const bool rowsel = (i < nn);
  const int rowbase = q0 - j0;            // (b*N + i)*N

  // p staged by kernel 1 at out_w[rowbase + nn]; only the thread whose span
  // contains column nn needs it (it reads before it overwrites - same thread).
  float pv = 0.0f;
  if (rowsel && nn >= j0 && nn < j0 + kElems) pv = out_w[rowbase + nn];

  const float4 wqa = *reinterpret_cast<const float4*>(weights + q0);
  const float4 wqb = *reinterpret_cast<const float4*>(weights + q0 + 4);
  float wvals[kElems] = {wqa.x, wqa.y, wqa.z, wqa.w, wqb.x, wqb.y, wqb.z, wqb.w};
  float ow[kElems];

  constexpr uint32_t kBitsThr = (8190000u << 9) | 511u;  // see soundness proof

#pragma unroll
  for (int ee = 0; ee < kElems; ++ee) {
    const int j = j0 + ee;
    const float w = (rowsel && (j == nn)) ? pv : wvals[ee];
    const uint32_t bits =
        random_bits_part((uint32_t)(q0 + ee) + (uint32_t)kHalf);
    ow[ee] = w;
    if ((w != 0.0f) || (bits > kBitsThr)) {
      uint32_t k = atomicAdd(&s_cnt, 1u);
      s_q[k] = (uint32_t)(q0 + ee);
      s_w[k] = w;
    }
  }

  const float4 z4 = make_float4(0.0f, 0.0f, 0.0f, 0.0f);
  *reinterpret_cast<float4*>(out_adj + q0) = z4;
  *reinterpret_cast<float4*>(out_adj + q0 + 4) = z4;
  {
    f32x4 v0 = {ow[0], ow[1], ow[2], ow[3]};
    f32x4 v1 = {ow[4], ow[5], ow[6], ow[7]};
    __builtin_nontemporal_store(v0, reinterpret_cast<f32x4*>(out_w + q0));
    __builtin_nontemporal_store(v1, reinterpret_cast<f32x4*>(out_w + q0 + 4));
  }

  __syncthreads();   // drains the stores above; publishes s_cnt/s_q/s_w

  const uint32_t n = s_cnt;
  for (uint32_t k = threadIdx.x; k < n; k += 256) {
    const uint32_t q = s_q[k];
    const float w = s_w[k];
    const float c1 = fminf(fmaxf(w, 0.001f), 0.999f);
    const float c0 = fminf(fmaxf(1.0f - w, 0.001f), 0.999f);
    if (decide_elem(q, c0, c1) > 0.5f) out_adj[q] = 1.0f;
  }
}

}  // namespace

extern "C" void kernel_launch(void* const* d_in, const int* in_sizes, int n_in,
                              void* d_out, int out_size, void* d_ws, size_t ws_size,
                              hipStream_t stream) {
  (void)in_sizes; (void)n_in; (void)out_size; (void)d_ws; (void)ws_size;
  const float* nodes = (const float*)d_in[0];
  // d_in[1] = adj (unused by reference)
  const float* weights = (const float*)d_in[2];
  const int* num_nodes = (const int*)d_in[3];
  // d_in[4] = B scalar (compile-time constant here)
  const float* W1 = (const float*)d_in[5];
  const float* b1 = (const float*)d_in[6];
  const float* W2 = (const float*)d_in[7];
  const float* b2 = (const float*)d_in[8];

  float* out_adj = (float*)d_out;
  float* out_w = out_adj + (size_t)kHalf;

  hipLaunchKernelGGL(mlp_probs_kernel, dim3(512), dim3(256), 0, stream,
                     nodes, num_nodes, W1, b1, W2, b2, out_w);
  hipLaunchKernelGGL(edge_screen_kernel, dim3(kScreenBlocks), dim3(256), 0, stream,
                     weights, num_nodes, out_adj, out_w);
}